// Round 7
// baseline (255.866 us; speedup 1.0000x reference)
//
#include <hip/hip_runtime.h>

// GraphSAGE 2-layer (mean agg), N=100K, E=1.6M, 128->128->64, f32 in/out.
// GEMMs in bf16 MFMA; gather (neighbor-mean) path in fp8 e4m3 (half traffic,
// cvt_pk_f32_fp8 = 2 elems/VALU-op). CSR via bucketed LDS counting sort.
// Layer1: agg8(h8) -> [hb|agg]@Wt1. Layer2: GEMM -> {p2 fp8, s2 f32},
// out = relu(s2 + mean-gather(p2)).
// NOTE: remainder shfl must be wave-uniform (ds_bpermute returns 0 for
// inactive source lanes) — guard only the load, never the shfl.

typedef __attribute__((ext_vector_type(8))) short short8;
typedef __attribute__((ext_vector_type(4))) float f32x4;
typedef __attribute__((ext_vector_type(2))) float f32x2;

__device__ __forceinline__ ushort f2bf(float f) {
  uint u = __float_as_uint(f);
  u += 0x7fffu + ((u >> 16) & 1u);  // round-to-nearest-even
  return (ushort)(u >> 16);
}
__device__ __forceinline__ float bl(uint u) { return __uint_as_float(u << 16); }
__device__ __forceinline__ float bh(uint u) { return __uint_as_float(u & 0xffff0000u); }

#define GLDS(src, dst)                                                        \
  __builtin_amdgcn_global_load_lds(                                           \
      (const __attribute__((address_space(1))) void*)(src),                   \
      (__attribute__((address_space(3))) void*)(dst), 16, 0, 0)

// ================= bucketed CSR build =================
__global__ __launch_bounds__(256) void k_bhist(const int* __restrict__ dst,
                                               int* __restrict__ bcnt, int E) {
  __shared__ int h[512];
  int t = threadIdx.x;
  for (int i = t; i < 512; i += 256) h[i] = 0;
  __syncthreads();
  int base = blockIdx.x * 8192;
  int end = min(base + 8192, E);
  for (int e = base + t; e < end; e += 256)
    atomicAdd(&h[((uint)dst[e]) >> 8], 1);
  __syncthreads();
  for (int i = t; i < 512; i += 256)
    if (h[i]) atomicAdd(&bcnt[i], h[i]);
}

__global__ __launch_bounds__(512) void k_bscan(const int* __restrict__ bcnt,
                                               int* __restrict__ bbase,
                                               int* __restrict__ bcur, int P, int E) {
  __shared__ int s[512];
  int t = threadIdx.x;
  int v = (t < P) ? bcnt[t] : 0;
  s[t] = v;
  __syncthreads();
  for (int off = 1; off < 512; off <<= 1) {
    int x = (t >= off) ? s[t - off] : 0;
    __syncthreads();
    s[t] += x;
    __syncthreads();
  }
  int ex = s[t] - v;
  if (t < P) {
    bbase[t] = ex;
    bcur[t] = ex;
  }
  if (t == P - 1) bbase[P] = E;
}

__global__ __launch_bounds__(256) void k_bscatter(const int* __restrict__ dst,
                                                  const int* __restrict__ src,
                                                  int* __restrict__ bcur,
                                                  uint* __restrict__ bed, int E, int P) {
  __shared__ int hist[512];
  __shared__ int incl[512];
  __shared__ int gpos[512];
  __shared__ int cur[512];
  __shared__ uint stage[8192];
  __shared__ ushort bof[8192];
  int t = threadIdx.x;
  int base = blockIdx.x * 8192;
  int cnt = min(8192, E - base);
  for (int i = t; i < 512; i += 256) hist[i] = 0;
  __syncthreads();
  for (int i = t; i < cnt; i += 256)
    atomicAdd(&hist[((uint)dst[base + i]) >> 8], 1);
  __syncthreads();
  incl[t] = hist[t];
  incl[t + 256] = hist[t + 256];
  __syncthreads();
  for (int off = 1; off < 512; off <<= 1) {
    int i0 = t, i1 = t + 256;
    int a0 = (i0 >= off) ? incl[i0 - off] : 0;
    int a1 = (i1 >= off) ? incl[i1 - off] : 0;
    __syncthreads();
    incl[i0] += a0;
    incl[i1] += a1;
    __syncthreads();
  }
  cur[t] = incl[t] - hist[t];
  cur[t + 256] = incl[t + 256] - hist[t + 256];
  for (int i = t; i < P; i += 256)
    if (hist[i]) gpos[i] = atomicAdd(&bcur[i], hist[i]);
  __syncthreads();
  for (int i = t; i < cnt; i += 256) {
    int d = dst[base + i];
    int b = ((uint)d) >> 8;
    uint val = (((uint)src[base + i]) << 8) | (uint)(d & 255);
    int slot = atomicAdd(&cur[b], 1);
    stage[slot] = val;
    bof[slot] = (ushort)b;
  }
  __syncthreads();
  for (int i = t; i < cnt; i += 256) {
    int b = bof[i];
    int ex = incl[b] - hist[b];
    bed[gpos[b] + (i - ex)] = stage[i];
  }
}

__global__ __launch_bounds__(256) void k_bcsr(const uint* __restrict__ bed,
                                              const int* __restrict__ bbase,
                                              int* __restrict__ deg,
                                              int* __restrict__ rs,
                                              int* __restrict__ col, int N) {
  __shared__ int dcnt[256];
  __shared__ int sofs[256];
  int b = blockIdx.x, t = threadIdx.x;
  int e0 = bbase[b], e1 = bbase[b + 1];
  dcnt[t] = 0;
  __syncthreads();
  for (int e = e0 + t; e < e1; e += 256) atomicAdd(&dcnt[bed[e] & 255u], 1);
  __syncthreads();
  int v0 = dcnt[t];
  sofs[t] = v0;
  __syncthreads();
  for (int off = 1; off < 256; off <<= 1) {
    int x = (t >= off) ? sofs[t - off] : 0;
    __syncthreads();
    sofs[t] += x;
    __syncthreads();
  }
  int ex = sofs[t] - v0;
  int node = (b << 8) + t;
  if (node < N) {
    deg[node] = v0;
    rs[node] = e0 + ex;
  }
  __syncthreads();
  dcnt[t] = e0 + ex;
  __syncthreads();
  for (int e = e0 + t; e < e1; e += 256) {
    uint v = bed[e];
    int pos = atomicAdd(&dcnt[v & 255u], 1);
    col[pos] = (int)(v >> 8);
  }
}

// -------- prep: f32 h -> bf16 hb (GEMM) + fp8 h8 (gather) --------
__global__ __launch_bounds__(256) void k_cast(const float* __restrict__ in,
                                              ushort* __restrict__ outb,
                                              uchar* __restrict__ out8, int n8) {
  int i = blockIdx.x * 256 + threadIdx.x;
  if (i >= n8) return;
  const float4* p = reinterpret_cast<const float4*>(in) + i * 2;
  float4 a = p[0], b = p[1];
  ushort u[8];
  u[0] = f2bf(a.x); u[1] = f2bf(a.y); u[2] = f2bf(a.z); u[3] = f2bf(a.w);
  u[4] = f2bf(b.x); u[5] = f2bf(b.y); u[6] = f2bf(b.z); u[7] = f2bf(b.w);
  *reinterpret_cast<ulonglong2*>(outb + (size_t)i * 8) =
      *reinterpret_cast<ulonglong2*>(u);
  uint2 q;
  int w0 = __builtin_amdgcn_cvt_pk_fp8_f32(a.x, a.y, 0, false);
  w0 = __builtin_amdgcn_cvt_pk_fp8_f32(a.z, a.w, w0, true);
  int w1 = __builtin_amdgcn_cvt_pk_fp8_f32(b.x, b.y, 0, false);
  w1 = __builtin_amdgcn_cvt_pk_fp8_f32(b.z, b.w, w1, true);
  q.x = (uint)w0;
  q.y = (uint)w1;
  *reinterpret_cast<uint2*>(out8 + (size_t)i * 8) = q;
}

// prep weights: Wt1[n][k0..255] = [Ws1;Wn1]^T ; Wt2cat[n][k0..127]:
// n<64 -> Wn2[k][n] (p2 half), n>=64 -> Ws2[k][n-64] (s2 half).
__global__ __launch_bounds__(256) void k_prep_w(const float* __restrict__ Ws1,
                                                const float* __restrict__ Wn1,
                                                const float* __restrict__ Ws2,
                                                const float* __restrict__ Wn2,
                                                ushort* __restrict__ Wt1,
                                                ushort* __restrict__ Wt2cat) {
  int idx = blockIdx.x * 256 + threadIdx.x;
  if (idx < 128 * 256) {
    int n = idx >> 8, k = idx & 255;
    float v = (k < 128) ? Ws1[(size_t)k * 128 + n] : Wn1[(size_t)(k - 128) * 128 + n];
    Wt1[idx] = f2bf(v);
  } else if (idx < 128 * 256 + 128 * 128) {
    int j = idx - 128 * 256;
    int n = j >> 7, k = j & 127;
    float v = (n < 64) ? Wn2[(size_t)k * 64 + n] : Ws2[(size_t)k * 64 + (n - 64)];
    Wt2cat[j] = f2bf(v);
  }
}

#define ACC16(v)                                                             \
  do {                                                                       \
    f32x2 f;                                                                 \
    f = __builtin_amdgcn_cvt_pk_f32_fp8((int)(v).x, false); a[0] += f.x; a[1] += f.y;  \
    f = __builtin_amdgcn_cvt_pk_f32_fp8((int)(v).x, true);  a[2] += f.x; a[3] += f.y;  \
    f = __builtin_amdgcn_cvt_pk_f32_fp8((int)(v).y, false); a[4] += f.x; a[5] += f.y;  \
    f = __builtin_amdgcn_cvt_pk_f32_fp8((int)(v).y, true);  a[6] += f.x; a[7] += f.y;  \
    f = __builtin_amdgcn_cvt_pk_f32_fp8((int)(v).z, false); a[8] += f.x; a[9] += f.y;  \
    f = __builtin_amdgcn_cvt_pk_f32_fp8((int)(v).z, true);  a[10] += f.x; a[11] += f.y;\
    f = __builtin_amdgcn_cvt_pk_f32_fp8((int)(v).w, false); a[12] += f.x; a[13] += f.y;\
    f = __builtin_amdgcn_cvt_pk_f32_fp8((int)(v).w, true);  a[14] += f.x; a[15] += f.y;\
  } while (0)

// -------- layer-1 aggregate: fp8 rows (128B); 8 rows/iter, 16B/lane --------
__global__ __launch_bounds__(256) void k_agg1(const uchar* __restrict__ X8,
                                              const int* __restrict__ col,
                                              const int* __restrict__ rs,
                                              const int* __restrict__ deg,
                                              ushort* __restrict__ outb, int n) {
  int node = blockIdx.x * 4 + (threadIdx.x >> 6);
  if (node >= n) return;
  int lane = threadIdx.x & 63;
  int grp = lane >> 3, sl = lane & 7;
  int r0 = rs[node], d = deg[node];
  float a[16] = {};
  int j = 0;
  while (j < d) {
    int cnt = min(d - j, 64);
    int myc = (lane < cnt) ? col[r0 + j + lane] : 0;
    int jj = 0;
    for (; jj + 8 <= cnt; jj += 8) {
      int c = __shfl(myc, jj + grp, 64);
      uint4 v = *reinterpret_cast<const uint4*>(X8 + (size_t)c * 128 + sl * 16);
      ACC16(v);
    }
    int rem = cnt - jj;
    if (rem > 0) {                        // wave-uniform branch
      int c = __shfl(myc, jj + grp, 64);  // all lanes execute the shfl
      if (grp < rem) {
        uint4 v = *reinterpret_cast<const uint4*>(X8 + (size_t)c * 128 + sl * 16);
        ACC16(v);
      }
    }
    j += cnt;
  }
#pragma unroll
  for (int k = 0; k < 16; k++) {
    a[k] += __shfl_xor(a[k], 8, 64);
    a[k] += __shfl_xor(a[k], 16, 64);
    a[k] += __shfl_xor(a[k], 32, 64);
  }
  if (grp == 0) {
    float rinv = 1.0f / fmaxf((float)d, 1.0f);
    ushort o[16];
#pragma unroll
    for (int k = 0; k < 16; k++) o[k] = f2bf(a[k] * rinv);
    ulonglong2* dst = reinterpret_cast<ulonglong2*>(outb + (size_t)node * 128 + sl * 16);
    dst[0] = reinterpret_cast<ulonglong2*>(o)[0];
    dst[1] = reinterpret_cast<ulonglong2*>(o)[1];
  }
}

// -------- layer-2 fused gather+add: fp8 rows (64B); 16 rows/iter ----------
__global__ __launch_bounds__(256) void k_agg_out(const uchar* __restrict__ P8,
                                                 const float* __restrict__ S,
                                                 const int* __restrict__ col,
                                                 const int* __restrict__ rs,
                                                 const int* __restrict__ deg,
                                                 float* __restrict__ out, int n) {
  int node = blockIdx.x * 4 + (threadIdx.x >> 6);
  if (node >= n) return;
  int lane = threadIdx.x & 63;
  int grp = lane >> 2, sl = lane & 3;
  int r0 = rs[node], d = deg[node];
  float a[16] = {};
  int j = 0;
  while (j < d) {
    int cnt = min(d - j, 64);
    int myc = (lane < cnt) ? col[r0 + j + lane] : 0;
    int jj = 0;
    for (; jj + 16 <= cnt; jj += 16) {
      int c = __shfl(myc, jj + grp, 64);
      uint4 v = *reinterpret_cast<const uint4*>(P8 + (size_t)c * 64 + sl * 16);
      ACC16(v);
    }
    int rem = cnt - jj;
    if (rem > 0) {                        // wave-uniform branch
      int c = __shfl(myc, jj + grp, 64);
      if (grp < rem) {
        uint4 v = *reinterpret_cast<const uint4*>(P8 + (size_t)c * 64 + sl * 16);
        ACC16(v);
      }
    }
    j += cnt;
  }
#pragma unroll
  for (int k = 0; k < 16; k++) {
    a[k] += __shfl_xor(a[k], 4, 64);
    a[k] += __shfl_xor(a[k], 8, 64);
    a[k] += __shfl_xor(a[k], 16, 64);
    a[k] += __shfl_xor(a[k], 32, 64);
  }
  if (grp == 0) {
    float rinv = 1.0f / fmaxf((float)d, 1.0f);
    const float4* sp = reinterpret_cast<const float4*>(S + (size_t)node * 64 + sl * 16);
    float4* op = reinterpret_cast<float4*>(out + (size_t)node * 64 + sl * 16);
#pragma unroll
    for (int q = 0; q < 4; q++) {
      float4 s = sp[q];
      float4 o;
      o.x = fmaxf(a[q * 4 + 0] * rinv + s.x, 0.f);
      o.y = fmaxf(a[q * 4 + 1] * rinv + s.y, 0.f);
      o.z = fmaxf(a[q * 4 + 2] * rinv + s.z, 0.f);
      o.w = fmaxf(a[q * 4 + 3] * rinv + s.w, 0.f);
      op[q] = o;
    }
  }
}

// ---------------- MFMA combine ----------------
// MODE 0: OutA = relu(X|G @ Wt + bias) bf16, BN cols.
// MODE 1: cols<64 -> OutA = fp8(acc) raw (p2); cols>=64 -> OutB = acc+bias f32 (s2).
template <int BN, int KCH, int MODE>
__global__ __launch_bounds__(256) void k_combine(const ushort* __restrict__ Xb,
                                                 const ushort* __restrict__ Gb,
                                                 const ushort* __restrict__ Wt,
                                                 const float* __restrict__ bias,
                                                 void* __restrict__ OutA,
                                                 void* __restrict__ OutB, int M) {
  constexpr int WTN = BN / 2;
  constexpr int FM = 4;
  constexpr int FN = WTN / 16;
  __shared__ char XsB[128 * 64 * 2];
  __shared__ char WsB[BN * 64 * 2];

  const int m0 = blockIdx.x * 128;
  const int t = threadIdx.x;
  const int lane = t & 63;
  const int w = t >> 6;
  const int wm = w >> 1, wn = w & 1;

  f32x4 acc[FM][FN] = {};

  for (int kc = 0; kc < KCH; kc++) {
    const ushort* Xsrc = (kc < 2) ? Xb : Gb;
    const int koff = (kc & 1) * 64;
#pragma unroll
    for (int i = 0; i < 4; i++) {
      int g = i * 256 + t;
      int row = g >> 3, kph = g & 7;
      int gm = min(m0 + row, M - 1);
      const ushort* src = Xsrc + (size_t)gm * 128 + koff + ((kph ^ (row & 7)) << 3);
      char* dst = XsB + ((i * 256 + (t & ~63)) << 4);
      GLDS(src, dst);
    }
#pragma unroll
    for (int i = 0; i < BN / 32; i++) {
      int g = i * 256 + t;
      int colr = g >> 3, kph = g & 7;
      const ushort* src =
          Wt + (size_t)colr * (KCH * 64) + kc * 64 + ((kph ^ (colr & 7)) << 3);
      char* dst = WsB + ((i * 256 + (t & ~63)) << 4);
      GLDS(src, dst);
    }
    __syncthreads();
#pragma unroll
    for (int ks = 0; ks < 2; ks++) {
      int kslot = ks * 4 + (lane >> 4);
      short8 af[FM], bf[FN];
#pragma unroll
      for (int fm = 0; fm < FM; fm++) {
        int row = wm * 64 + fm * 16 + (lane & 15);
        af[fm] = *reinterpret_cast<const short8*>(
            XsB + row * 128 + ((kslot ^ (row & 7)) << 4));
      }
#pragma unroll
      for (int fn = 0; fn < FN; fn++) {
        int colr = wn * WTN + fn * 16 + (lane & 15);
        bf[fn] = *reinterpret_cast<const short8*>(
            WsB + colr * 128 + ((kslot ^ (colr & 7)) << 4));
      }
#pragma unroll
      for (int fm = 0; fm < FM; fm++)
#pragma unroll
        for (int fn = 0; fn < FN; fn++)
          acc[fm][fn] = __builtin_amdgcn_mfma_f32_16x16x32_bf16(
              af[fm], bf[fn], acc[fm][fn], 0, 0, 0);
    }
    __syncthreads();
  }

#pragma unroll
  for (int fn = 0; fn < FN; fn++) {
    int colg = wn * WTN + fn * 16 + (lane & 15);
    float bb;
    if constexpr (MODE == 0) bb = bias[colg];
    else bb = (colg >= 64) ? bias[colg - 64] : 0.f;
#pragma unroll
    for (int fm = 0; fm < FM; fm++) {
#pragma unroll
      for (int r = 0; r < 4; r++) {
        int rowg = m0 + wm * 64 + fm * 16 + (lane >> 4) * 4 + r;
        if (rowg >= M) continue;
        if constexpr (MODE == 0) {
          float v = fmaxf(acc[fm][fn][r] + bb, 0.f);
          ((ushort*)OutA)[(size_t)rowg * BN + colg] = f2bf(v);
        } else {
          if (colg < 64) {
            float v = acc[fm][fn][r];
            int b8 = __builtin_amdgcn_cvt_pk_fp8_f32(v, v, 0, false);
            ((uchar*)OutA)[(size_t)rowg * 64 + colg] = (uchar)(b8 & 0xff);
          } else {
            ((float*)OutB)[(size_t)rowg * 64 + (colg - 64)] = acc[fm][fn][r] + bb;
          }
        }
      }
    }
  }
}

extern "C" void kernel_launch(void* const* d_in, const int* in_sizes, int n_in,
                              void* d_out, int out_size, void* d_ws, size_t ws_size,
                              hipStream_t stream) {
  const float* h = (const float*)d_in[0];
  const int* esrc = (const int*)d_in[1];
  const int* edst = (const int*)d_in[2];
  const float* Ws1 = (const float*)d_in[3];
  const float* Wn1 = (const float*)d_in[4];
  const float* b1 = (const float*)d_in[5];
  const float* Ws2 = (const float*)d_in[6];
  const float* Wn2 = (const float*)d_in[7];
  const float* b2 = (const float*)d_in[8];
  float* out = (float*)d_out;

  const int N = in_sizes[0] / 128;  // 100000
  const int E = in_sizes[1];        // 1600000
  const int P = (N + 255) >> 8;     // 391 buckets (<=512)

  char* base = (char*)d_ws;
  size_t off = 0;
  auto alloc = [&](size_t bytes) {
    size_t o = off;
    off += (bytes + 255) & ~(size_t)255;
    return o;
  };
  int* deg = (int*)(base + alloc((size_t)N * 4));
  int* rs = (int*)(base + alloc((size_t)N * 4));
  int* bcnt = (int*)(base + alloc(513 * 4));
  int* bbase = (int*)(base + alloc(513 * 4));
  int* bcur = (int*)(base + alloc(513 * 4));
  uint* bed = (uint*)(base + alloc((size_t)E * 4));
  int* col = (int*)(base + alloc((size_t)E * 4));
  ushort* hb = (ushort*)(base + alloc((size_t)N * 128 * 2));
  uchar* h8 = (uchar*)(base + alloc((size_t)N * 128));
  ushort* aggb = (ushort*)(base + alloc((size_t)N * 128 * 2));
  ushort* h1b = (ushort*)(base + alloc((size_t)N * 128 * 2));
  ushort* Wt1 = (ushort*)(base + alloc(128 * 256 * 2));
  ushort* Wt2cat = (ushort*)(base + alloc(128 * 128 * 2));
  // overlays (regions dead by the time they're written):
  uchar* p8 = (uchar*)hb;    // layer-2 p2 [N][64] fp8 (hb last read by combine1)
  float* s2f = (float*)aggb; // layer-2 s2 [N][64] f32 (aggb last read by combine1)

  const int NCH = (E + 8191) / 8192;

  (void)hipMemsetAsync(bcnt, 0, 513 * 4, stream);
  k_bhist<<<NCH, 256, 0, stream>>>(edst, bcnt, E);
  k_bscan<<<1, 512, 0, stream>>>(bcnt, bbase, bcur, P, E);
  k_bscatter<<<NCH, 256, 0, stream>>>(edst, esrc, bcur, bed, E, P);
  k_bcsr<<<P, 256, 0, stream>>>(bed, bbase, deg, rs, col, N);

  k_prep_w<<<((128 * 256 + 128 * 128) + 255) / 256, 256, 0, stream>>>(
      Ws1, Wn1, Ws2, Wn2, Wt1, Wt2cat);
  k_cast<<<((N * 128 / 8) + 255) / 256, 256, 0, stream>>>(h, hb, h8, N * 128 / 8);

  // Layer 1
  k_agg1<<<(N + 3) / 4, 256, 0, stream>>>(h8, col, rs, deg, aggb, N);
  k_combine<128, 4, 0><<<(N + 127) / 128, 256, 0, stream>>>(hb, aggb, Wt1, b1,
                                                            h1b, nullptr, N);
  // Layer 2: one K=128 GEMM -> p2 (fp8) + s2 (f32), then fused gather+add+relu
  k_combine<128, 2, 1><<<(N + 127) / 128, 256, 0, stream>>>(h1b, nullptr, Wt2cat,
                                                            b2, p8, s2f, N);
  k_agg_out<<<(N + 3) / 4, 256, 0, stream>>>(p8, s2f, col, rs, deg, out, N);
}

// Round 8
// 196.810 us; speedup vs baseline: 1.3001x; 1.3001x over previous
//
#include <hip/hip_runtime.h>

// GraphSAGE 2-layer (mean agg), N=100K, E=1.6M, 128->128->64, f32 in/out.
// GEMMs in bf16 MFMA; gather path in fp8 e4m3. CSR via bucketed counting sort.
// Gathers use one 16-lane group per node (4 nodes/wave): lane owns a fixed
// 1/16 row-slice -> in-lane accumulation (no cross-lane reduce), x4-unrolled
// neighbor loop = many loads in flight (R7 was latency-bound at ~1 load/wave).
// Shfl sources are always in-group => active (group-uniform loop bounds).

typedef __attribute__((ext_vector_type(8))) short short8;
typedef __attribute__((ext_vector_type(4))) float f32x4;
typedef __attribute__((ext_vector_type(2))) float f32x2;

__device__ __forceinline__ ushort f2bf(float f) {
  uint u = __float_as_uint(f);
  u += 0x7fffu + ((u >> 16) & 1u);  // round-to-nearest-even
  return (ushort)(u >> 16);
}

#define GLDS(src, dst)                                                        \
  __builtin_amdgcn_global_load_lds(                                           \
      (const __attribute__((address_space(1))) void*)(src),                   \
      (__attribute__((address_space(3))) void*)(dst), 16, 0, 0)

// ================= bucketed CSR build =================
__global__ __launch_bounds__(256) void k_bhist(const int* __restrict__ dst,
                                               int* __restrict__ bcnt, int E) {
  __shared__ int h[512];
  int t = threadIdx.x;
  for (int i = t; i < 512; i += 256) h[i] = 0;
  __syncthreads();
  int base = blockIdx.x * 8192;
  int end = min(base + 8192, E);
  for (int e = base + t; e < end; e += 256)
    atomicAdd(&h[((uint)dst[e]) >> 8], 1);
  __syncthreads();
  for (int i = t; i < 512; i += 256)
    if (h[i]) atomicAdd(&bcnt[i], h[i]);
}

__global__ __launch_bounds__(512) void k_bscan(const int* __restrict__ bcnt,
                                               int* __restrict__ bbase,
                                               int* __restrict__ bcur, int P, int E) {
  __shared__ int s[512];
  int t = threadIdx.x;
  int v = (t < P) ? bcnt[t] : 0;
  s[t] = v;
  __syncthreads();
  for (int off = 1; off < 512; off <<= 1) {
    int x = (t >= off) ? s[t - off] : 0;
    __syncthreads();
    s[t] += x;
    __syncthreads();
  }
  int ex = s[t] - v;
  if (t < P) {
    bbase[t] = ex;
    bcur[t] = ex;
  }
  if (t == P - 1) bbase[P] = E;
}

__global__ __launch_bounds__(256) void k_bscatter(const int* __restrict__ dst,
                                                  const int* __restrict__ src,
                                                  int* __restrict__ bcur,
                                                  uint* __restrict__ bed, int E, int P) {
  __shared__ int hist[512];
  __shared__ int incl[512];
  __shared__ int gpos[512];
  __shared__ int cur[512];
  __shared__ uint stage[8192];
  __shared__ ushort bof[8192];
  int t = threadIdx.x;
  int base = blockIdx.x * 8192;
  int cnt = min(8192, E - base);
  for (int i = t; i < 512; i += 256) hist[i] = 0;
  __syncthreads();
  for (int i = t; i < cnt; i += 256)
    atomicAdd(&hist[((uint)dst[base + i]) >> 8], 1);
  __syncthreads();
  incl[t] = hist[t];
  incl[t + 256] = hist[t + 256];
  __syncthreads();
  for (int off = 1; off < 512; off <<= 1) {
    int i0 = t, i1 = t + 256;
    int a0 = (i0 >= off) ? incl[i0 - off] : 0;
    int a1 = (i1 >= off) ? incl[i1 - off] : 0;
    __syncthreads();
    incl[i0] += a0;
    incl[i1] += a1;
    __syncthreads();
  }
  cur[t] = incl[t] - hist[t];
  cur[t + 256] = incl[t + 256] - hist[t + 256];
  for (int i = t; i < P; i += 256)
    if (hist[i]) gpos[i] = atomicAdd(&bcur[i], hist[i]);
  __syncthreads();
  for (int i = t; i < cnt; i += 256) {
    int d = dst[base + i];
    int b = ((uint)d) >> 8;
    uint val = (((uint)src[base + i]) << 8) | (uint)(d & 255);
    int slot = atomicAdd(&cur[b], 1);
    stage[slot] = val;
    bof[slot] = (ushort)b;
  }
  __syncthreads();
  for (int i = t; i < cnt; i += 256) {
    int b = bof[i];
    int ex = incl[b] - hist[b];
    bed[gpos[b] + (i - ex)] = stage[i];
  }
}

__global__ __launch_bounds__(256) void k_bcsr(const uint* __restrict__ bed,
                                              const int* __restrict__ bbase,
                                              int* __restrict__ deg,
                                              int* __restrict__ rs,
                                              int* __restrict__ col, int N) {
  __shared__ int dcnt[256];
  __shared__ int sofs[256];
  int b = blockIdx.x, t = threadIdx.x;
  int e0 = bbase[b], e1 = bbase[b + 1];
  dcnt[t] = 0;
  __syncthreads();
  for (int e = e0 + t; e < e1; e += 256) atomicAdd(&dcnt[bed[e] & 255u], 1);
  __syncthreads();
  int v0 = dcnt[t];
  sofs[t] = v0;
  __syncthreads();
  for (int off = 1; off < 256; off <<= 1) {
    int x = (t >= off) ? sofs[t - off] : 0;
    __syncthreads();
    sofs[t] += x;
    __syncthreads();
  }
  int ex = sofs[t] - v0;
  int node = (b << 8) + t;
  if (node < N) {
    deg[node] = v0;
    rs[node] = e0 + ex;
  }
  __syncthreads();
  dcnt[t] = e0 + ex;
  __syncthreads();
  for (int e = e0 + t; e < e1; e += 256) {
    uint v = bed[e];
    int pos = atomicAdd(&dcnt[v & 255u], 1);
    col[pos] = (int)(v >> 8);
  }
}

// -------- prep: f32 h -> bf16 hb (GEMM) + fp8 h8 (gather) --------
__global__ __launch_bounds__(256) void k_cast(const float* __restrict__ in,
                                              ushort* __restrict__ outb,
                                              uchar* __restrict__ out8, int n8) {
  int i = blockIdx.x * 256 + threadIdx.x;
  if (i >= n8) return;
  const float4* p = reinterpret_cast<const float4*>(in) + i * 2;
  float4 a = p[0], b = p[1];
  ushort u[8];
  u[0] = f2bf(a.x); u[1] = f2bf(a.y); u[2] = f2bf(a.z); u[3] = f2bf(a.w);
  u[4] = f2bf(b.x); u[5] = f2bf(b.y); u[6] = f2bf(b.z); u[7] = f2bf(b.w);
  *reinterpret_cast<ulonglong2*>(outb + (size_t)i * 8) =
      *reinterpret_cast<ulonglong2*>(u);
  uint2 q;
  int w0 = __builtin_amdgcn_cvt_pk_fp8_f32(a.x, a.y, 0, false);
  w0 = __builtin_amdgcn_cvt_pk_fp8_f32(a.z, a.w, w0, true);
  int w1 = __builtin_amdgcn_cvt_pk_fp8_f32(b.x, b.y, 0, false);
  w1 = __builtin_amdgcn_cvt_pk_fp8_f32(b.z, b.w, w1, true);
  q.x = (uint)w0;
  q.y = (uint)w1;
  *reinterpret_cast<uint2*>(out8 + (size_t)i * 8) = q;
}

// prep weights: Wt1[n][k0..255] = [Ws1;Wn1]^T ; Wt2cat[n][k0..127]:
// n<64 -> Wn2[k][n] (p2 half), n>=64 -> Ws2[k][n-64] (s2 half).
__global__ __launch_bounds__(256) void k_prep_w(const float* __restrict__ Ws1,
                                                const float* __restrict__ Wn1,
                                                const float* __restrict__ Ws2,
                                                const float* __restrict__ Wn2,
                                                ushort* __restrict__ Wt1,
                                                ushort* __restrict__ Wt2cat) {
  int idx = blockIdx.x * 256 + threadIdx.x;
  if (idx < 128 * 256) {
    int n = idx >> 8, k = idx & 255;
    float v = (k < 128) ? Ws1[(size_t)k * 128 + n] : Wn1[(size_t)(k - 128) * 128 + n];
    Wt1[idx] = f2bf(v);
  } else if (idx < 128 * 256 + 128 * 128) {
    int j = idx - 128 * 256;
    int n = j >> 7, k = j & 127;
    float v = (n < 64) ? Wn2[(size_t)k * 64 + n] : Ws2[(size_t)k * 64 + (n - 64)];
    Wt2cat[j] = f2bf(v);
  }
}

#define ACC8(v)                                                                \
  do {                                                                         \
    f32x2 f;                                                                   \
    f = __builtin_amdgcn_cvt_pk_f32_fp8((int)(v).x, false); a[0] += f.x; a[1] += f.y; \
    f = __builtin_amdgcn_cvt_pk_f32_fp8((int)(v).x, true);  a[2] += f.x; a[3] += f.y; \
    f = __builtin_amdgcn_cvt_pk_f32_fp8((int)(v).y, false); a[4] += f.x; a[5] += f.y; \
    f = __builtin_amdgcn_cvt_pk_f32_fp8((int)(v).y, true);  a[6] += f.x; a[7] += f.y; \
  } while (0)

#define ACC4(v)                                                                \
  do {                                                                         \
    f32x2 f;                                                                   \
    f = __builtin_amdgcn_cvt_pk_f32_fp8((int)(v), false); a[0] += f.x; a[1] += f.y;   \
    f = __builtin_amdgcn_cvt_pk_f32_fp8((int)(v), true);  a[2] += f.x; a[3] += f.y;   \
  } while (0)

// -------- layer-1 aggregate: fp8 128B rows; 16-lane group per node ---------
// lane sl owns bytes [sl*8, sl*8+8) of every neighbor row; in-lane accum.
__global__ __launch_bounds__(256) void k_agg1(const uchar* __restrict__ X8,
                                              const int* __restrict__ col,
                                              const int* __restrict__ rs,
                                              const int* __restrict__ deg,
                                              ushort* __restrict__ outb, int n) {
  int node = blockIdx.x * 16 + (threadIdx.x >> 4);
  if (node >= n) return;
  int sl = threadIdx.x & 15;
  int gbase = (threadIdx.x & 63) & ~15;  // group base lane within wave
  int r0 = rs[node], d = deg[node];
  float a[8] = {};
  int j = 0;
  while (j < d) {  // group-uniform bound
    int cnt = min(d - j, 16);
    int myc = (sl < cnt) ? col[r0 + j + sl] : 0;
    int jj = 0;
    for (; jj + 4 <= cnt; jj += 4) {
      int c0 = __shfl(myc, gbase + jj + 0, 64);
      int c1 = __shfl(myc, gbase + jj + 1, 64);
      int c2 = __shfl(myc, gbase + jj + 2, 64);
      int c3 = __shfl(myc, gbase + jj + 3, 64);
      uint2 v0 = *reinterpret_cast<const uint2*>(X8 + (size_t)c0 * 128 + sl * 8);
      uint2 v1 = *reinterpret_cast<const uint2*>(X8 + (size_t)c1 * 128 + sl * 8);
      uint2 v2 = *reinterpret_cast<const uint2*>(X8 + (size_t)c2 * 128 + sl * 8);
      uint2 v3 = *reinterpret_cast<const uint2*>(X8 + (size_t)c3 * 128 + sl * 8);
      ACC8(v0); ACC8(v1); ACC8(v2); ACC8(v3);
    }
    for (; jj < cnt; jj++) {  // group-uniform tail
      int c0 = __shfl(myc, gbase + jj, 64);
      uint2 v0 = *reinterpret_cast<const uint2*>(X8 + (size_t)c0 * 128 + sl * 8);
      ACC8(v0);
    }
    j += cnt;
  }
  float rinv = 1.0f / fmaxf((float)d, 1.0f);
  ushort o[8];
#pragma unroll
  for (int k = 0; k < 8; k++) o[k] = f2bf(a[k] * rinv);
  *reinterpret_cast<ulonglong2*>(outb + (size_t)node * 128 + sl * 8) =
      *reinterpret_cast<ulonglong2*>(o);
}

// -------- layer-2 fused gather+add: fp8 64B rows; 16-lane group per node ---
// lane sl owns bytes [sl*4, sl*4+4); out = relu(s2 + mean-gather(p2)).
__global__ __launch_bounds__(256) void k_agg_out(const uchar* __restrict__ P8,
                                                 const float* __restrict__ S,
                                                 const int* __restrict__ col,
                                                 const int* __restrict__ rs,
                                                 const int* __restrict__ deg,
                                                 float* __restrict__ out, int n) {
  int node = blockIdx.x * 16 + (threadIdx.x >> 4);
  if (node >= n) return;
  int sl = threadIdx.x & 15;
  int gbase = (threadIdx.x & 63) & ~15;
  int r0 = rs[node], d = deg[node];
  float a[4] = {};
  int j = 0;
  while (j < d) {
    int cnt = min(d - j, 16);
    int myc = (sl < cnt) ? col[r0 + j + sl] : 0;
    int jj = 0;
    for (; jj + 4 <= cnt; jj += 4) {
      int c0 = __shfl(myc, gbase + jj + 0, 64);
      int c1 = __shfl(myc, gbase + jj + 1, 64);
      int c2 = __shfl(myc, gbase + jj + 2, 64);
      int c3 = __shfl(myc, gbase + jj + 3, 64);
      uint v0 = *reinterpret_cast<const uint*>(P8 + (size_t)c0 * 64 + sl * 4);
      uint v1 = *reinterpret_cast<const uint*>(P8 + (size_t)c1 * 64 + sl * 4);
      uint v2 = *reinterpret_cast<const uint*>(P8 + (size_t)c2 * 64 + sl * 4);
      uint v3 = *reinterpret_cast<const uint*>(P8 + (size_t)c3 * 64 + sl * 4);
      ACC4(v0); ACC4(v1); ACC4(v2); ACC4(v3);
    }
    for (; jj < cnt; jj++) {
      int c0 = __shfl(myc, gbase + jj, 64);
      uint v0 = *reinterpret_cast<const uint*>(P8 + (size_t)c0 * 64 + sl * 4);
      ACC4(v0);
    }
    j += cnt;
  }
  float rinv = 1.0f / fmaxf((float)d, 1.0f);
  float4 s = *reinterpret_cast<const float4*>(S + (size_t)node * 64 + sl * 4);
  float4 o;
  o.x = fmaxf(a[0] * rinv + s.x, 0.f);
  o.y = fmaxf(a[1] * rinv + s.y, 0.f);
  o.z = fmaxf(a[2] * rinv + s.z, 0.f);
  o.w = fmaxf(a[3] * rinv + s.w, 0.f);
  *reinterpret_cast<float4*>(out + (size_t)node * 64 + sl * 4) = o;
}

// ---------------- MFMA combine ----------------
// MODE 0: OutA = relu(X|G @ Wt + bias) bf16, BN cols.
// MODE 1: cols<64 -> OutA = fp8(acc) raw (p2); cols>=64 -> OutB = acc+bias f32 (s2).
template <int BN, int KCH, int MODE>
__global__ __launch_bounds__(256) void k_combine(const ushort* __restrict__ Xb,
                                                 const ushort* __restrict__ Gb,
                                                 const ushort* __restrict__ Wt,
                                                 const float* __restrict__ bias,
                                                 void* __restrict__ OutA,
                                                 void* __restrict__ OutB, int M) {
  constexpr int WTN = BN / 2;
  constexpr int FM = 4;
  constexpr int FN = WTN / 16;
  __shared__ char XsB[128 * 64 * 2];
  __shared__ char WsB[BN * 64 * 2];

  const int m0 = blockIdx.x * 128;
  const int t = threadIdx.x;
  const int lane = t & 63;
  const int w = t >> 6;
  const int wm = w >> 1, wn = w & 1;

  f32x4 acc[FM][FN] = {};

  for (int kc = 0; kc < KCH; kc++) {
    const ushort* Xsrc = (kc < 2) ? Xb : Gb;
    const int koff = (kc & 1) * 64;
#pragma unroll
    for (int i = 0; i < 4; i++) {
      int g = i * 256 + t;
      int row = g >> 3, kph = g & 7;
      int gm = min(m0 + row, M - 1);
      const ushort* src = Xsrc + (size_t)gm * 128 + koff + ((kph ^ (row & 7)) << 3);
      char* dst = XsB + ((i * 256 + (t & ~63)) << 4);
      GLDS(src, dst);
    }
#pragma unroll
    for (int i = 0; i < BN / 32; i++) {
      int g = i * 256 + t;
      int colr = g >> 3, kph = g & 7;
      const ushort* src =
          Wt + (size_t)colr * (KCH * 64) + kc * 64 + ((kph ^ (colr & 7)) << 3);
      char* dst = WsB + ((i * 256 + (t & ~63)) << 4);
      GLDS(src, dst);
    }
    __syncthreads();
#pragma unroll
    for (int ks = 0; ks < 2; ks++) {
      int kslot = ks * 4 + (lane >> 4);
      short8 af[FM], bf[FN];
#pragma unroll
      for (int fm = 0; fm < FM; fm++) {
        int row = wm * 64 + fm * 16 + (lane & 15);
        af[fm] = *reinterpret_cast<const short8*>(
            XsB + row * 128 + ((kslot ^ (row & 7)) << 4));
      }
#pragma unroll
      for (int fn = 0; fn < FN; fn++) {
        int colr = wn * WTN + fn * 16 + (lane & 15);
        bf[fn] = *reinterpret_cast<const short8*>(
            WsB + colr * 128 + ((kslot ^ (colr & 7)) << 4));
      }
#pragma unroll
      for (int fm = 0; fm < FM; fm++)
#pragma unroll
        for (int fn = 0; fn < FN; fn++)
          acc[fm][fn] = __builtin_amdgcn_mfma_f32_16x16x32_bf16(
              af[fm], bf[fn], acc[fm][fn], 0, 0, 0);
    }
    __syncthreads();
  }

#pragma unroll
  for (int fn = 0; fn < FN; fn++) {
    int colg = wn * WTN + fn * 16 + (lane & 15);
    float bb;
    if constexpr (MODE == 0) bb = bias[colg];
    else bb = (colg >= 64) ? bias[colg - 64] : 0.f;
#pragma unroll
    for (int fm = 0; fm < FM; fm++) {
#pragma unroll
      for (int r = 0; r < 4; r++) {
        int rowg = m0 + wm * 64 + fm * 16 + (lane >> 4) * 4 + r;
        if (rowg >= M) continue;
        if constexpr (MODE == 0) {
          float v = fmaxf(acc[fm][fn][r] + bb, 0.f);
          ((ushort*)OutA)[(size_t)rowg * BN + colg] = f2bf(v);
        } else {
          if (colg < 64) {
            float v = acc[fm][fn][r];
            int b8 = __builtin_amdgcn_cvt_pk_fp8_f32(v, v, 0, false);
            ((uchar*)OutA)[(size_t)rowg * 64 + colg] = (uchar)(b8 & 0xff);
          } else {
            ((float*)OutB)[(size_t)rowg * 64 + (colg - 64)] = acc[fm][fn][r] + bb;
          }
        }
      }
    }
  }
}

extern "C" void kernel_launch(void* const* d_in, const int* in_sizes, int n_in,
                              void* d_out, int out_size, void* d_ws, size_t ws_size,
                              hipStream_t stream) {
  const float* h = (const float*)d_in[0];
  const int* esrc = (const int*)d_in[1];
  const int* edst = (const int*)d_in[2];
  const float* Ws1 = (const float*)d_in[3];
  const float* Wn1 = (const float*)d_in[4];
  const float* b1 = (const float*)d_in[5];
  const float* Ws2 = (const float*)d_in[6];
  const float* Wn2 = (const float*)d_in[7];
  const float* b2 = (const float*)d_in[8];
  float* out = (float*)d_out;

  const int N = in_sizes[0] / 128;  // 100000
  const int E = in_sizes[1];        // 1600000
  const int P = (N + 255) >> 8;     // 391 buckets (<=512)

  char* base = (char*)d_ws;
  size_t off = 0;
  auto alloc = [&](size_t bytes) {
    size_t o = off;
    off += (bytes + 255) & ~(size_t)255;
    return o;
  };
  int* deg = (int*)(base + alloc((size_t)N * 4));
  int* rs = (int*)(base + alloc((size_t)N * 4));
  int* bcnt = (int*)(base + alloc(513 * 4));
  int* bbase = (int*)(base + alloc(513 * 4));
  int* bcur = (int*)(base + alloc(513 * 4));
  uint* bed = (uint*)(base + alloc((size_t)E * 4));
  int* col = (int*)(base + alloc((size_t)E * 4));
  ushort* hb = (ushort*)(base + alloc((size_t)N * 128 * 2));
  uchar* h8 = (uchar*)(base + alloc((size_t)N * 128));
  ushort* aggb = (ushort*)(base + alloc((size_t)N * 128 * 2));
  ushort* h1b = (ushort*)(base + alloc((size_t)N * 128 * 2));
  ushort* Wt1 = (ushort*)(base + alloc(128 * 256 * 2));
  ushort* Wt2cat = (ushort*)(base + alloc(128 * 128 * 2));
  // overlays (regions dead by the time they're written):
  uchar* p8 = (uchar*)hb;    // layer-2 p2 [N][64] fp8 (hb last read by combine1)
  float* s2f = (float*)aggb; // layer-2 s2 [N][64] f32 (aggb last read by combine1)

  const int NCH = (E + 8191) / 8192;

  (void)hipMemsetAsync(bcnt, 0, 513 * 4, stream);
  k_bhist<<<NCH, 256, 0, stream>>>(edst, bcnt, E);
  k_bscan<<<1, 512, 0, stream>>>(bcnt, bbase, bcur, P, E);
  k_bscatter<<<NCH, 256, 0, stream>>>(edst, esrc, bcur, bed, E, P);
  k_bcsr<<<P, 256, 0, stream>>>(bed, bbase, deg, rs, col, N);

  k_prep_w<<<((128 * 256 + 128 * 128) + 255) / 256, 256, 0, stream>>>(
      Ws1, Wn1, Ws2, Wn2, Wt1, Wt2cat);
  k_cast<<<((N * 128 / 8) + 255) / 256, 256, 0, stream>>>(h, hb, h8, N * 128 / 8);

  // Layer 1
  k_agg1<<<(N + 15) / 16, 256, 0, stream>>>(h8, col, rs, deg, aggb, N);
  k_combine<128, 4, 0><<<(N + 127) / 128, 256, 0, stream>>>(hb, aggb, Wt1, b1,
                                                            h1b, nullptr, N);
  // Layer 2: one K=128 GEMM -> p2 (fp8) + s2 (f32), then fused gather+add+relu
  k_combine<128, 2, 1><<<(N + 127) / 128, 256, 0, stream>>>(h1b, nullptr, Wt2cat,
                                                            b2, p8, s2f, N);
  k_agg_out<<<(N + 15) / 16, 256, 0, stream>>>(p8, s2f, col, rs, deg, out, N);
}

// Round 9
// 189.649 us; speedup vs baseline: 1.3492x; 1.0378x over previous
//
#include <hip/hip_runtime.h>

// GraphSAGE 2-layer (mean agg), N=100K, E=1.6M, 128->128->64, f32 in/out.
// GEMMs in bf16 MFMA, FUSED: GEMM1 (K=256, [h|agg]@Wt1,+b1,relu) -> h1 tile in
// LDS -> GEMM2 (K=128, h1@Wt2cat) -> {p2 fp8, s2 f32} in one kernel (no h1 HBM
// round trip). Gather path fp8 e4m3, lane-group-per-node (8 lanes L1, 4 lanes L2)
// for high memory-level parallelism. CSR via bucketed LDS counting sort.
// Overlays: p8->bed (dead after CSR), s2f->aggb (same row stride; block i
// overwrites exactly the rows it read -> WAR-safe within block, disjoint across).

typedef __attribute__((ext_vector_type(8))) short short8;
typedef __attribute__((ext_vector_type(4))) float f32x4;
typedef __attribute__((ext_vector_type(2))) float f32x2;

__device__ __forceinline__ ushort f2bf(float f) {
  uint u = __float_as_uint(f);
  u += 0x7fffu + ((u >> 16) & 1u);  // round-to-nearest-even
  return (ushort)(u >> 16);
}

#define GLDS(src, dst)                                                        \
  __builtin_amdgcn_global_load_lds(                                           \
      (const __attribute__((address_space(1))) void*)(src),                   \
      (__attribute__((address_space(3))) void*)(dst), 16, 0, 0)

// ================= bucketed CSR build =================
__global__ __launch_bounds__(256) void k_bhist(const int* __restrict__ dst,
                                               int* __restrict__ bcnt, int E) {
  __shared__ int h[512];
  int t = threadIdx.x;
  for (int i = t; i < 512; i += 256) h[i] = 0;
  __syncthreads();
  int base = blockIdx.x * 8192;
  int end = min(base + 8192, E);
  for (int e = base + t; e < end; e += 256)
    atomicAdd(&h[((uint)dst[e]) >> 8], 1);
  __syncthreads();
  for (int i = t; i < 512; i += 256)
    if (h[i]) atomicAdd(&bcnt[i], h[i]);
}

__global__ __launch_bounds__(512) void k_bscan(const int* __restrict__ bcnt,
                                               int* __restrict__ bbase,
                                               int* __restrict__ bcur, int P, int E) {
  __shared__ int s[512];
  int t = threadIdx.x;
  int v = (t < P) ? bcnt[t] : 0;
  s[t] = v;
  __syncthreads();
  for (int off = 1; off < 512; off <<= 1) {
    int x = (t >= off) ? s[t - off] : 0;
    __syncthreads();
    s[t] += x;
    __syncthreads();
  }
  int ex = s[t] - v;
  if (t < P) {
    bbase[t] = ex;
    bcur[t] = ex;
  }
  if (t == P - 1) bbase[P] = E;
}

__global__ __launch_bounds__(256) void k_bscatter(const int* __restrict__ dst,
                                                  const int* __restrict__ src,
                                                  int* __restrict__ bcur,
                                                  uint* __restrict__ bed, int E, int P) {
  __shared__ int hist[512];
  __shared__ int incl[512];
  __shared__ int gpos[512];
  __shared__ int cur[512];
  __shared__ uint stage[8192];
  __shared__ ushort bof[8192];
  int t = threadIdx.x;
  int base = blockIdx.x * 8192;
  int cnt = min(8192, E - base);
  for (int i = t; i < 512; i += 256) hist[i] = 0;
  __syncthreads();
  for (int i = t; i < cnt; i += 256)
    atomicAdd(&hist[((uint)dst[base + i]) >> 8], 1);
  __syncthreads();
  incl[t] = hist[t];
  incl[t + 256] = hist[t + 256];
  __syncthreads();
  for (int off = 1; off < 512; off <<= 1) {
    int i0 = t, i1 = t + 256;
    int a0 = (i0 >= off) ? incl[i0 - off] : 0;
    int a1 = (i1 >= off) ? incl[i1 - off] : 0;
    __syncthreads();
    incl[i0] += a0;
    incl[i1] += a1;
    __syncthreads();
  }
  cur[t] = incl[t] - hist[t];
  cur[t + 256] = incl[t + 256] - hist[t + 256];
  for (int i = t; i < P; i += 256)
    if (hist[i]) gpos[i] = atomicAdd(&bcur[i], hist[i]);
  __syncthreads();
  for (int i = t; i < cnt; i += 256) {
    int d = dst[base + i];
    int b = ((uint)d) >> 8;
    uint val = (((uint)src[base + i]) << 8) | (uint)(d & 255);
    int slot = atomicAdd(&cur[b], 1);
    stage[slot] = val;
    bof[slot] = (ushort)b;
  }
  __syncthreads();
  for (int i = t; i < cnt; i += 256) {
    int b = bof[i];
    int ex = incl[b] - hist[b];
    bed[gpos[b] + (i - ex)] = stage[i];
  }
}

__global__ __launch_bounds__(256) void k_bcsr(const uint* __restrict__ bed,
                                              const int* __restrict__ bbase,
                                              int* __restrict__ deg,
                                              int* __restrict__ rs,
                                              int* __restrict__ col, int N) {
  __shared__ int dcnt[256];
  __shared__ int sofs[256];
  int b = blockIdx.x, t = threadIdx.x;
  int e0 = bbase[b], e1 = bbase[b + 1];
  dcnt[t] = 0;
  __syncthreads();
  for (int e = e0 + t; e < e1; e += 256) atomicAdd(&dcnt[bed[e] & 255u], 1);
  __syncthreads();
  int v0 = dcnt[t];
  sofs[t] = v0;
  __syncthreads();
  for (int off = 1; off < 256; off <<= 1) {
    int x = (t >= off) ? sofs[t - off] : 0;
    __syncthreads();
    sofs[t] += x;
    __syncthreads();
  }
  int ex = sofs[t] - v0;
  int node = (b << 8) + t;
  if (node < N) {
    deg[node] = v0;
    rs[node] = e0 + ex;
  }
  __syncthreads();
  dcnt[t] = e0 + ex;
  __syncthreads();
  for (int e = e0 + t; e < e1; e += 256) {
    uint v = bed[e];
    int pos = atomicAdd(&dcnt[v & 255u], 1);
    col[pos] = (int)(v >> 8);
  }
}

// -------- prep: f32 h -> bf16 hb (GEMM) + fp8 h8 (gather) --------
__global__ __launch_bounds__(256) void k_cast(const float* __restrict__ in,
                                              ushort* __restrict__ outb,
                                              uchar* __restrict__ out8, int n8) {
  int i = blockIdx.x * 256 + threadIdx.x;
  if (i >= n8) return;
  const float4* p = reinterpret_cast<const float4*>(in) + i * 2;
  float4 a = p[0], b = p[1];
  ushort u[8];
  u[0] = f2bf(a.x); u[1] = f2bf(a.y); u[2] = f2bf(a.z); u[3] = f2bf(a.w);
  u[4] = f2bf(b.x); u[5] = f2bf(b.y); u[6] = f2bf(b.z); u[7] = f2bf(b.w);
  *reinterpret_cast<ulonglong2*>(outb + (size_t)i * 8) =
      *reinterpret_cast<ulonglong2*>(u);
  uint2 q;
  int w0 = __builtin_amdgcn_cvt_pk_fp8_f32(a.x, a.y, 0, false);
  w0 = __builtin_amdgcn_cvt_pk_fp8_f32(a.z, a.w, w0, true);
  int w1 = __builtin_amdgcn_cvt_pk_fp8_f32(b.x, b.y, 0, false);
  w1 = __builtin_amdgcn_cvt_pk_fp8_f32(b.z, b.w, w1, true);
  q.x = (uint)w0;
  q.y = (uint)w1;
  *reinterpret_cast<uint2*>(out8 + (size_t)i * 8) = q;
}

// prep weights: Wt1[n][k0..255] = [Ws1;Wn1]^T ; Wt2cat[n][k0..127]:
// n<64 -> Wn2[k][n] (p2 half), n>=64 -> Ws2[k][n-64] (s2 half).
__global__ __launch_bounds__(256) void k_prep_w(const float* __restrict__ Ws1,
                                                const float* __restrict__ Wn1,
                                                const float* __restrict__ Ws2,
                                                const float* __restrict__ Wn2,
                                                ushort* __restrict__ Wt1,
                                                ushort* __restrict__ Wt2cat) {
  int idx = blockIdx.x * 256 + threadIdx.x;
  if (idx < 128 * 256) {
    int n = idx >> 8, k = idx & 255;
    float v = (k < 128) ? Ws1[(size_t)k * 128 + n] : Wn1[(size_t)(k - 128) * 128 + n];
    Wt1[idx] = f2bf(v);
  } else if (idx < 128 * 256 + 128 * 128) {
    int j = idx - 128 * 256;
    int n = j >> 7, k = j & 127;
    float v = (n < 64) ? Wn2[(size_t)k * 64 + n] : Ws2[(size_t)k * 64 + (n - 64)];
    Wt2cat[j] = f2bf(v);
  }
}

#define ACC16(v)                                                               \
  do {                                                                         \
    f32x2 f;                                                                   \
    f = __builtin_amdgcn_cvt_pk_f32_fp8((int)(v).x, false); a[0] += f.x; a[1] += f.y;  \
    f = __builtin_amdgcn_cvt_pk_f32_fp8((int)(v).x, true);  a[2] += f.x; a[3] += f.y;  \
    f = __builtin_amdgcn_cvt_pk_f32_fp8((int)(v).y, false); a[4] += f.x; a[5] += f.y;  \
    f = __builtin_amdgcn_cvt_pk_f32_fp8((int)(v).y, true);  a[6] += f.x; a[7] += f.y;  \
    f = __builtin_amdgcn_cvt_pk_f32_fp8((int)(v).z, false); a[8] += f.x; a[9] += f.y;  \
    f = __builtin_amdgcn_cvt_pk_f32_fp8((int)(v).z, true);  a[10] += f.x; a[11] += f.y;\
    f = __builtin_amdgcn_cvt_pk_f32_fp8((int)(v).w, false); a[12] += f.x; a[13] += f.y;\
    f = __builtin_amdgcn_cvt_pk_f32_fp8((int)(v).w, true);  a[14] += f.x; a[15] += f.y;\
  } while (0)

// -------- layer-1 aggregate: fp8 128B rows; 8-lane group per node ---------
// lane sl owns bytes [sl*16, sl*16+16); 8 independent chains/wave.
__global__ __launch_bounds__(256) void k_agg1(const uchar* __restrict__ X8,
                                              const int* __restrict__ col,
                                              const int* __restrict__ rs,
                                              const int* __restrict__ deg,
                                              ushort* __restrict__ outb, int n) {
  int node = blockIdx.x * 32 + (threadIdx.x >> 3);
  if (node >= n) return;
  int sl = threadIdx.x & 7;
  int gbase = (threadIdx.x & 63) & ~7;  // group base lane within wave
  int r0 = rs[node], d = deg[node];
  float a[16] = {};
  int j = 0;
  while (j < d) {  // group-uniform bound (d uniform within group)
    int cnt = min(d - j, 8);
    int myc = (sl < cnt) ? col[r0 + j + sl] : 0;
    int jj = 0;
    for (; jj + 4 <= cnt; jj += 4) {
      int c0 = __shfl(myc, gbase + jj + 0, 64);
      int c1 = __shfl(myc, gbase + jj + 1, 64);
      int c2 = __shfl(myc, gbase + jj + 2, 64);
      int c3 = __shfl(myc, gbase + jj + 3, 64);
      uint4 v0 = *reinterpret_cast<const uint4*>(X8 + (size_t)c0 * 128 + sl * 16);
      uint4 v1 = *reinterpret_cast<const uint4*>(X8 + (size_t)c1 * 128 + sl * 16);
      uint4 v2 = *reinterpret_cast<const uint4*>(X8 + (size_t)c2 * 128 + sl * 16);
      uint4 v3 = *reinterpret_cast<const uint4*>(X8 + (size_t)c3 * 128 + sl * 16);
      { uint4 v = v0; ACC16(v); }
      { uint4 v = v1; ACC16(v); }
      { uint4 v = v2; ACC16(v); }
      { uint4 v = v3; ACC16(v); }
    }
    for (; jj < cnt; jj++) {  // group-uniform tail; shfl sources in-group, active
      int c0 = __shfl(myc, gbase + jj, 64);
      uint4 v = *reinterpret_cast<const uint4*>(X8 + (size_t)c0 * 128 + sl * 16);
      ACC16(v);
    }
    j += cnt;
  }
  float rinv = 1.0f / fmaxf((float)d, 1.0f);
  ushort o[16];
#pragma unroll
  for (int k = 0; k < 16; k++) o[k] = f2bf(a[k] * rinv);
  ulonglong2* dst = reinterpret_cast<ulonglong2*>(outb + (size_t)node * 128 + sl * 16);
  dst[0] = reinterpret_cast<ulonglong2*>(o)[0];
  dst[1] = reinterpret_cast<ulonglong2*>(o)[1];
}

// -------- layer-2 fused gather+add: fp8 64B rows; 4-lane group per node ----
// lane sl owns bytes [sl*16, sl*16+16); out = relu(s2 + mean-gather(p2)).
__global__ __launch_bounds__(256) void k_agg_out(const uchar* __restrict__ P8,
                                                 const float* __restrict__ S,
                                                 const int* __restrict__ col,
                                                 const int* __restrict__ rs,
                                                 const int* __restrict__ deg,
                                                 float* __restrict__ out, int n) {
  int node = blockIdx.x * 64 + (threadIdx.x >> 2);
  if (node >= n) return;
  int sl = threadIdx.x & 3;
  int gbase = (threadIdx.x & 63) & ~3;
  int r0 = rs[node], d = deg[node];
  float a[16] = {};
  int j = 0;
  while (j < d) {
    int cnt = min(d - j, 4);
    int myc = (sl < cnt) ? col[r0 + j + sl] : 0;
    int jj = 0;
    for (; jj + 4 <= cnt; jj += 4) {
      int c0 = __shfl(myc, gbase + 0, 64);
      int c1 = __shfl(myc, gbase + 1, 64);
      int c2 = __shfl(myc, gbase + 2, 64);
      int c3 = __shfl(myc, gbase + 3, 64);
      uint4 v0 = *reinterpret_cast<const uint4*>(P8 + (size_t)c0 * 64 + sl * 16);
      uint4 v1 = *reinterpret_cast<const uint4*>(P8 + (size_t)c1 * 64 + sl * 16);
      uint4 v2 = *reinterpret_cast<const uint4*>(P8 + (size_t)c2 * 64 + sl * 16);
      uint4 v3 = *reinterpret_cast<const uint4*>(P8 + (size_t)c3 * 64 + sl * 16);
      { uint4 v = v0; ACC16(v); }
      { uint4 v = v1; ACC16(v); }
      { uint4 v = v2; ACC16(v); }
      { uint4 v = v3; ACC16(v); }
    }
    for (; jj < cnt; jj++) {
      int c0 = __shfl(myc, gbase + jj, 64);
      uint4 v = *reinterpret_cast<const uint4*>(P8 + (size_t)c0 * 64 + sl * 16);
      ACC16(v);
    }
    j += cnt;
  }
  float rinv = 1.0f / fmaxf((float)d, 1.0f);
  const float4* sp = reinterpret_cast<const float4*>(S + (size_t)node * 64 + sl * 16);
  float4* op = reinterpret_cast<float4*>(out + (size_t)node * 64 + sl * 16);
#pragma unroll
  for (int q = 0; q < 4; q++) {
    float4 s = sp[q];
    float4 o;
    o.x = fmaxf(a[q * 4 + 0] * rinv + s.x, 0.f);
    o.y = fmaxf(a[q * 4 + 1] * rinv + s.y, 0.f);
    o.z = fmaxf(a[q * 4 + 2] * rinv + s.z, 0.f);
    o.w = fmaxf(a[q * 4 + 3] * rinv + s.w, 0.f);
    op[q] = o;
  }
}

// ---------------- FUSED MFMA combine: both layers' GEMMs ----------------
// GEMM1: [Xb|Gb] (K=256) @ Wt1 -> +b1, relu -> h1 tile into LDS Xs2 (bf16,
// granule-XOR swizzled). GEMM2: Xs2 (K=128) @ Wt2cat -> cols<64: p2 fp8;
// cols>=64: s2 = acc + b2 (f32). No h1 HBM round trip.
__global__ __launch_bounds__(256) void k_fused(const ushort* __restrict__ Xb,
                                               const ushort* __restrict__ Gb,
                                               const ushort* __restrict__ Wt1,
                                               const ushort* __restrict__ Wt2,
                                               const float* __restrict__ b1,
                                               const float* __restrict__ b2,
                                               uchar* __restrict__ P8,
                                               float* __restrict__ S2, int M) {
  __shared__ char XsB[128 * 64 * 2];   // 16 KB: X-tile chunk
  __shared__ char WsB[128 * 64 * 2];   // 16 KB: W-tile chunk (reused by GEMM2)
  __shared__ char Xs2[128 * 128 * 2];  // 32 KB: h1 tile (K for GEMM2)

  const int m0 = blockIdx.x * 128;
  const int t = threadIdx.x;
  const int lane = t & 63;
  const int w = t >> 6;
  const int wm = w >> 1, wn = w & 1;

  f32x4 acc[4][4] = {};

  // ---- GEMM1: K=256 over [Xb | Gb] ----
  for (int kc = 0; kc < 4; kc++) {
    const ushort* Xsrc = (kc < 2) ? Xb : Gb;
    const int koff = (kc & 1) * 64;
#pragma unroll
    for (int i = 0; i < 4; i++) {
      int g = i * 256 + t;
      int row = g >> 3, kph = g & 7;
      int gm = min(m0 + row, M - 1);
      const ushort* src = Xsrc + (size_t)gm * 128 + koff + ((kph ^ (row & 7)) << 3);
      char* dst = XsB + ((i * 256 + (t & ~63)) << 4);
      GLDS(src, dst);
    }
#pragma unroll
    for (int i = 0; i < 4; i++) {
      int g = i * 256 + t;
      int colr = g >> 3, kph = g & 7;
      const ushort* src = Wt1 + (size_t)colr * 256 + kc * 64 + ((kph ^ (colr & 7)) << 3);
      char* dst = WsB + ((i * 256 + (t & ~63)) << 4);
      GLDS(src, dst);
    }
    __syncthreads();
#pragma unroll
    for (int ks = 0; ks < 2; ks++) {
      int kslot = ks * 4 + (lane >> 4);
      short8 af[4], bf[4];
#pragma unroll
      for (int fm = 0; fm < 4; fm++) {
        int row = wm * 64 + fm * 16 + (lane & 15);
        af[fm] = *reinterpret_cast<const short8*>(
            XsB + row * 128 + ((kslot ^ (row & 7)) << 4));
      }
#pragma unroll
      for (int fn = 0; fn < 4; fn++) {
        int colr = wn * 64 + fn * 16 + (lane & 15);
        bf[fn] = *reinterpret_cast<const short8*>(
            WsB + colr * 128 + ((kslot ^ (colr & 7)) << 4));
      }
#pragma unroll
      for (int fm = 0; fm < 4; fm++)
#pragma unroll
        for (int fn = 0; fn < 4; fn++)
          acc[fm][fn] = __builtin_amdgcn_mfma_f32_16x16x32_bf16(
              af[fm], bf[fn], acc[fm][fn], 0, 0, 0);
    }
    __syncthreads();
  }

  // ---- epilogue 1: h1 = relu(acc + b1) -> Xs2 (swizzled bf16) ----
#pragma unroll
  for (int fn = 0; fn < 4; fn++) {
    int colg = wn * 64 + fn * 16 + (lane & 15);
    float bb = b1[colg];
    int g = colg >> 3;
    int cb = (colg & 7) * 2;
#pragma unroll
    for (int fm = 0; fm < 4; fm++) {
#pragma unroll
      for (int r = 0; r < 4; r++) {
        int rowl = wm * 64 + fm * 16 + (lane >> 4) * 4 + r;
        ushort hv = f2bf(fmaxf(acc[fm][fn][r] + bb, 0.f));
        *reinterpret_cast<ushort*>(Xs2 + rowl * 256 + ((g ^ (rowl & 15)) << 4) + cb) = hv;
      }
    }
  }
  __syncthreads();

  // ---- GEMM2: K=128 from Xs2; W2 chunks through WsB ----
  f32x4 acc2[4][4] = {};
  for (int kc = 0; kc < 2; kc++) {
#pragma unroll
    for (int i = 0; i < 4; i++) {
      int g = i * 256 + t;
      int colr = g >> 3, kph = g & 7;
      const ushort* src = Wt2 + (size_t)colr * 128 + kc * 64 + ((kph ^ (colr & 7)) << 3);
      char* dst = WsB + ((i * 256 + (t & ~63)) << 4);
      GLDS(src, dst);
    }
    __syncthreads();
#pragma unroll
    for (int ks = 0; ks < 2; ks++) {
      int kslot = ks * 4 + (lane >> 4);
      short8 af[4], bf[4];
#pragma unroll
      for (int fm = 0; fm < 4; fm++) {
        int row = wm * 64 + fm * 16 + (lane & 15);
        int gk = kc * 8 + kslot;
        af[fm] = *reinterpret_cast<const short8*>(
            Xs2 + row * 256 + ((gk ^ (row & 15)) << 4));
      }
#pragma unroll
      for (int fn = 0; fn < 4; fn++) {
        int colr = wn * 64 + fn * 16 + (lane & 15);
        bf[fn] = *reinterpret_cast<const short8*>(
            WsB + colr * 128 + ((kslot ^ (colr & 7)) << 4));
      }
#pragma unroll
      for (int fm = 0; fm < 4; fm++)
#pragma unroll
        for (int fn = 0; fn < 4; fn++)
          acc2[fm][fn] = __builtin_amdgcn_mfma_f32_16x16x32_bf16(
              af[fm], bf[fn], acc2[fm][fn], 0, 0, 0);
    }
    __syncthreads();
  }

  // ---- epilogue 2: split p2 (fp8) / s2 (f32 + b2) ----
#pragma unroll
  for (int fn = 0; fn < 4; fn++) {
    int colg = wn * 64 + fn * 16 + (lane & 15);
    float bb = (colg >= 64) ? b2[colg - 64] : 0.f;
#pragma unroll
    for (int fm = 0; fm < 4; fm++) {
#pragma unroll
      for (int r = 0; r < 4; r++) {
        int rowg = m0 + wm * 64 + fm * 16 + (lane >> 4) * 4 + r;
        if (rowg >= M) continue;
        if (colg < 64) {
          float v = acc2[fm][fn][r];
          int b8 = __builtin_amdgcn_cvt_pk_fp8_f32(v, v, 0, false);
          P8[(size_t)rowg * 64 + colg] = (uchar)(b8 & 0xff);
        } else {
          S2[(size_t)rowg * 64 + (colg - 64)] = acc2[fm][fn][r] + bb;
        }
      }
    }
  }
}

extern "C" void kernel_launch(void* const* d_in, const int* in_sizes, int n_in,
                              void* d_out, int out_size, void* d_ws, size_t ws_size,
                              hipStream_t stream) {
  const float* h = (const float*)d_in[0];
  const int* esrc = (const int*)d_in[1];
  const int* edst = (const int*)d_in[2];
  const float* Ws1 = (const float*)d_in[3];
  const float* Wn1 = (const float*)d_in[4];
  const float* b1 = (const float*)d_in[5];
  const float* Ws2 = (const float*)d_in[6];
  const float* Wn2 = (const float*)d_in[7];
  const float* b2 = (const float*)d_in[8];
  float* out = (float*)d_out;

  const int N = in_sizes[0] / 128;  // 100000
  const int E = in_sizes[1];        // 1600000
  const int P = (N + 255) >> 8;     // 391 buckets (<=512)

  char* base = (char*)d_ws;
  size_t off = 0;
  auto alloc = [&](size_t bytes) {
    size_t o = off;
    off += (bytes + 255) & ~(size_t)255;
    return o;
  };
  int* deg = (int*)(base + alloc((size_t)N * 4));
  int* rs = (int*)(base + alloc((size_t)N * 4));
  int* bcnt = (int*)(base + alloc(513 * 4));
  int* bbase = (int*)(base + alloc(513 * 4));
  int* bcur = (int*)(base + alloc(513 * 4));
  uint* bed = (uint*)(base + alloc((size_t)E * 4));
  int* col = (int*)(base + alloc((size_t)E * 4));
  ushort* hb = (ushort*)(base + alloc((size_t)N * 128 * 2));
  uchar* h8 = (uchar*)(base + alloc((size_t)N * 128));
  ushort* aggb = (ushort*)(base + alloc((size_t)N * 128 * 2));
  ushort* Wt1 = (ushort*)(base + alloc(128 * 256 * 2));
  ushort* Wt2cat = (ushort*)(base + alloc(128 * 128 * 2));
  // overlays:
  uchar* p8 = (uchar*)bed;   // [N][64] fp8: bed dead after k_bcsr; N*64 <= E*4
  float* s2f = (float*)aggb; // [N][64] f32: same 256B row stride as aggb; fused
                             // block overwrites exactly the rows it read (safe)

  const int NCH = (E + 8191) / 8192;

  (void)hipMemsetAsync(bcnt, 0, 513 * 4, stream);
  k_bhist<<<NCH, 256, 0, stream>>>(edst, bcnt, E);
  k_bscan<<<1, 512, 0, stream>>>(bcnt, bbase, bcur, P, E);
  k_bscatter<<<NCH, 256, 0, stream>>>(edst, esrc, bcur, bed, E, P);
  k_bcsr<<<P, 256, 0, stream>>>(bed, bbase, deg, rs, col, N);

  k_prep_w<<<((128 * 256 + 128 * 128) + 255) / 256, 256, 0, stream>>>(
      Ws1, Wn1, Ws2, Wn2, Wt1, Wt2cat);
  k_cast<<<((N * 128 / 8) + 255) / 256, 256, 0, stream>>>(h, hb, h8, N * 128 / 8);

  // Layer 1 aggregate, then fused GEMM1+GEMM2 -> p2 (fp8) + s2 (f32)
  k_agg1<<<(N + 31) / 32, 256, 0, stream>>>(h8, col, rs, deg, aggb, N);
  k_fused<<<(N + 127) / 128, 256, 0, stream>>>(hb, aggb, Wt1, Wt2cat, b1, b2,
                                               p8, s2f, N);
  // Layer 2 fused gather + add + relu
  k_agg_out<<<(N + 63) / 64, 256, 0, stream>>>(p8, s2f, col, rs, deg, out, N);
}